// Round 9
// baseline (694.626 us; speedup 1.0000x reference)
//
#include <hip/hip_runtime.h>
#include <math.h>

// Problem dims
#define S_LEN 2048
#define D_HEAD 64
#define BH 32
#define ROWS 8      // strip rows per block; 33KB LDS -> 4 blocks/CU

typedef __attribute__((ext_vector_type(8))) short short8;    // 8 bf16 (4 VGPR)
typedef __attribute__((ext_vector_type(4))) short short4v;   // 8B LDS chunk
typedef __attribute__((ext_vector_type(4))) float f32x4;
typedef __attribute__((ext_vector_type(2))) float f32x2;

// LDS row stride in bf16 elems: 4104B rows -> 8B aligned, +2-bank row shift
#define SPAD 2052

__device__ __forceinline__ short f2bf(float f) {
  union { float f; unsigned u; } a; a.f = f;
  unsigned u = a.u;
  unsigned r = (u + 0x7fffu + ((u >> 16) & 1u)) >> 16;   // RNE, no NaNs here
  return (short)r;
}
__device__ __forceinline__ float bf2f(unsigned short h) {
  union { unsigned u; float f; } a; a.u = ((unsigned)h) << 16; return a.f;
}
__device__ __forceinline__ f32x4 ntl4(const float* p) { return __builtin_nontemporal_load((const f32x4*)p); }
__device__ __forceinline__ void  nts4(float* p, f32x4 v) { __builtin_nontemporal_store(v, (f32x4*)p); }
__device__ __forceinline__ void  nts2(float* p, f32x2 v) { __builtin_nontemporal_store(v, (f32x2*)p); }

// ---------------------------------------------------------------------------
// Kernel T: K [bh][64][2048] -> kT [bh][2048][64] bf16 ; V [bh][2048][64] ->
// vT [bh][64][2048] bf16. Fully coalesced both sides.
// ---------------------------------------------------------------------------
__global__ __launch_bounds__(256) void transpose_kernel(
    const float* __restrict__ kin, const float* __restrict__ vin,
    unsigned short* __restrict__ kT, unsigned short* __restrict__ vT)
{
  __shared__ float tile[64][65];
  const int bh = blockIdx.y;
  const int bx = blockIdx.x;
  const int t  = threadIdx.x;

  if (blockIdx.z == 0) {
    const float* in = kin + (size_t)bh * D_HEAD * S_LEN;
    #pragma unroll
    for (int p = 0; p < 4; ++p) {
      const int row = p * 16 + (t >> 4);
      f32x4 f = ntl4(in + (size_t)row * S_LEN + bx * 64 + (t & 15) * 4);
      tile[row][(t & 15) * 4 + 0] = f.x; tile[row][(t & 15) * 4 + 1] = f.y;
      tile[row][(t & 15) * 4 + 2] = f.z; tile[row][(t & 15) * 4 + 3] = f.w;
    }
    __syncthreads();
    union { unsigned short h[16]; uint4 q[2]; } u;
    #pragma unroll
    for (int i = 0; i < 16; ++i) u.h[i] = (unsigned short)f2bf(tile[(t & 3) * 16 + i][t >> 2]);
    uint4* dst = (uint4*)(kT + (size_t)bh * S_LEN * D_HEAD
                             + (size_t)(bx * 64 + (t >> 2)) * D_HEAD + (t & 3) * 16);
    dst[0] = u.q[0]; dst[1] = u.q[1];
  } else {
    const float* in = vin + (size_t)bh * S_LEN * D_HEAD;
    #pragma unroll
    for (int p = 0; p < 4; ++p) {
      const int row = p * 16 + (t >> 4);
      f32x4 f = ntl4(in + (size_t)(bx * 64 + row) * D_HEAD + (t & 15) * 4);
      tile[row][(t & 15) * 4 + 0] = f.x; tile[row][(t & 15) * 4 + 1] = f.y;
      tile[row][(t & 15) * 4 + 2] = f.z; tile[row][(t & 15) * 4 + 3] = f.w;
    }
    __syncthreads();
    union { unsigned short h[16]; uint4 q[2]; } u;
    #pragma unroll
    for (int i = 0; i < 16; ++i) u.h[i] = (unsigned short)f2bf(tile[(t & 3) * 16 + i][t >> 2]);
    uint4* dst = (uint4*)(vT + (size_t)bh * D_HEAD * S_LEN
                             + (size_t)(t >> 2) * S_LEN + bx * 64 + (t & 3) * 16);
    dst[0] = u.q[0]; dst[1] = u.q[1];
  }
}

// ---------------------------------------------------------------------------
// Fused kernel, 8-row strip / block, 4 waves col-split 512, 4 blocks/CU.
//  P1 : QK^T MFMA (A rows lr&7 duplicated; C rows 8..15 discarded) ->
//       bf16(qk) into LDS rows 0..7.
//  P2 : coalesced (32 lanes per row, thread = 4 consecutive floats ->
//       512B contiguous per instruction): prev NT load, s = qk*scale+prev,
//       scores NT store, e = exp(s) -> LDS, row-sum via 5 shfl_xor.
//  P3+P4 fused: weights = e*rl NT store (HBM) interleaved with PV MFMA
//       (A = e from LDS rows lr&7, B = vT via L2).
//  Epilogue: merge 4 waves' partial O via LDS alias, scale by rl, NT store.
// ---------------------------------------------------------------------------
__global__ __launch_bounds__(256, 4) void fused_kernel(
    const float* __restrict__ q, const unsigned short* __restrict__ kT,
    const float* __restrict__ prev, const float* __restrict__ scale_p,
    const unsigned short* __restrict__ vT,
    float* __restrict__ scores, float* __restrict__ weights, float* __restrict__ outO)
{
  __shared__ union {
    unsigned short s[ROWS][SPAD];   // 32832 B
    float om[4][ROWS][68];          // 8704 B (aliased after P4 LDS reads)
  } sh;
  __shared__ float rlv[ROWS];

  const int bh   = blockIdx.y;
  const int m0   = blockIdx.x * ROWS;
  const int tid  = threadIdx.x;
  const int w    = tid >> 6;
  const int lane = tid & 63;
  const int lr   = lane & 15;
  const int lg   = lane >> 4;
  const float scale = scale_p[0];

  // Q A-frags: row = m0 + (lr&7), d = kk*32 + lg*8 + j
  short8 aq[2];
  {
    const float* qrow = q + ((size_t)bh * S_LEN + m0 + (lr & 7)) * D_HEAD;
    #pragma unroll
    for (int kk = 0; kk < 2; ++kk) {
      f32x4 f0 = *(const f32x4*)(qrow + kk * 32 + lg * 8);
      f32x4 f1 = *(const f32x4*)(qrow + kk * 32 + lg * 8 + 4);
      short8 a;
      a[0]=f2bf(f0.x); a[1]=f2bf(f0.y); a[2]=f2bf(f0.z); a[3]=f2bf(f0.w);
      a[4]=f2bf(f1.x); a[5]=f2bf(f1.y); a[6]=f2bf(f1.z); a[7]=f2bf(f1.w);
      aq[kk] = a;
    }
  }

  // P2 mapping: row owned by an aligned 32-lane group; thread = 4 consecutive
  // floats; one instruction = 32 lanes x 16B = 512B contiguous (full lines).
  const int row = tid >> 5;          // 0..7
  const int cq  = (tid & 31) * 4;    // 0..124
  const size_t rowoff = (size_t)bh * S_LEN * S_LEN + (size_t)(m0 + row) * S_LEN;
  const float* prevrow = prev + rowoff;
  // prefetch prev u=0..3 (in flight across all of P1)
  f32x4 pf0 = ntl4(prevrow + cq);
  f32x4 pf1 = ntl4(prevrow + cq + 128);
  f32x4 pf2 = ntl4(prevrow + cq + 256);
  f32x4 pf3 = ntl4(prevrow + cq + 384);

  const unsigned short* kbase = kT + (size_t)bh * S_LEN * D_HEAD;

  // ---------------- P1: QK^T -> LDS (bf16 raw products) ----------------
  #pragma unroll 2
  for (int t8 = 0; t8 < 8; ++t8) {
    const int n0 = w * 512 + t8 * 64;
    f32x4 acc[4];
    #pragma unroll
    for (int nt = 0; nt < 4; ++nt) acc[nt] = (f32x4){0.f, 0.f, 0.f, 0.f};

    #pragma unroll
    for (int kk = 0; kk < 2; ++kk) {
      #pragma unroll
      for (int nt = 0; nt < 4; ++nt) {
        const short8 b = *(const short8*)(
            kbase + (size_t)(n0 + nt * 16 + lr) * D_HEAD + kk * 32 + lg * 8);
        acc[nt] = __builtin_amdgcn_mfma_f32_16x16x32_bf16(aq[kk], b, acc[nt], 0, 0, 0);
      }
    }
    if (lg < 2) {   // C rows 0..7 (8..15 duplicate)
      #pragma unroll
      for (int nt = 0; nt < 4; ++nt)
        #pragma unroll
        for (int rg = 0; rg < 4; ++rg)
          sh.s[lg * 4 + rg][n0 + nt * 16 + lr] = (unsigned short)f2bf(acc[nt][rg]);
    }
  }
  __syncthreads();

  // ---------------- P2: scores out + e=exp(s) into LDS + row-sum ----------
  float* srow = scores + rowoff;
  float sum = 0.f;
  #pragma unroll 4
  for (int u = 0; u < 16; ++u) {
    const int c = cq + u * 128;
    short4v h = *(const short4v*)&sh.s[row][c];
    f32x4 p = (u == 0) ? pf0 : (u == 1) ? pf1 : (u == 2) ? pf2 : (u == 3) ? pf3
                       : ntl4(prevrow + c);
    f32x4 s;
    s.x = bf2f((unsigned short)h[0]) * scale + p.x;
    s.y = bf2f((unsigned short)h[1]) * scale + p.y;
    s.z = bf2f((unsigned short)h[2]) * scale + p.z;
    s.w = bf2f((unsigned short)h[3]) * scale + p.w;
    nts4(srow + c, s);
    const float e0 = __expf(s.x), e1 = __expf(s.y), e2 = __expf(s.z), e3 = __expf(s.w);
    sum += (e0 + e1) + (e2 + e3);
    short4v g;
    g[0] = f2bf(e0); g[1] = f2bf(e1); g[2] = f2bf(e2); g[3] = f2bf(e3);
    *(short4v*)&sh.s[row][c] = g;
  }

  // row-sum across the 32-lane group (same wave, aligned)
  #pragma unroll
  for (int msk = 1; msk <= 16; msk <<= 1)
    sum += __shfl_xor(sum, msk, 64);
  const float rl = 1.0f / sum;
  if ((tid & 31) == 0) rlv[row] = rl;
  __syncthreads();

  // ---------------- P3+P4 fused: weights store ∥ PV MFMA ----------------
  const unsigned short* vbase = vT + (size_t)bh * D_HEAD * S_LEN;
  float* wrow = weights + rowoff;
  f32x4 accp[4];
  #pragma unroll
  for (int ct = 0; ct < 4; ++ct) accp[ct] = (f32x4){0.f, 0.f, 0.f, 0.f};

  #pragma unroll 2
  for (int i = 0; i < 16; ++i) {
    // P4 part: A = e fragment from LDS (rows lr&7), B = vT (L2)
    const int c4 = w * 512 + i * 32 + lg * 8;
    short4v h0 = *(const short4v*)&sh.s[lr & 7][c4];
    short4v h1 = *(const short4v*)&sh.s[lr & 7][c4 + 4];
    short8 a;
    a[0]=h0[0]; a[1]=h0[1]; a[2]=h0[2]; a[3]=h0[3];
    a[4]=h1[0]; a[5]=h1[1]; a[6]=h1[2]; a[7]=h1[3];
    #pragma unroll
    for (int ct = 0; ct < 4; ++ct) {
      const short8 b = *(const short8*)(vbase + (size_t)(ct * 16 + lr) * S_LEN + c4);
      accp[ct] = __builtin_amdgcn_mfma_f32_16x16x32_bf16(a, b, accp[ct], 0, 0, 0);
    }
    // P3 part: weights = e * rl (own row, independent of P4)
    const int c = cq + i * 128;
    short4v hw = *(const short4v*)&sh.s[row][c];
    f32x4 e;
    e.x = bf2f((unsigned short)hw[0]) * rl;
    e.y = bf2f((unsigned short)hw[1]) * rl;
    e.z = bf2f((unsigned short)hw[2]) * rl;
    e.w = bf2f((unsigned short)hw[3]) * rl;
    nts4(wrow + c, e);
  }
  __syncthreads();   // all sh.s reads done; safe to alias sh.om

  if (lg < 2) {
    #pragma unroll
    for (int ct = 0; ct < 4; ++ct)
      #pragma unroll
      for (int rg = 0; rg < 4; ++rg)
        sh.om[w][lg * 4 + rg][ct * 16 + lr] = accp[ct][rg];
  }
  __syncthreads();

  {
    const int d2  = (tid & 31) * 2;
    const float rls = rlv[row];
    f32x2 v;
    v.x = (sh.om[0][row][d2]     + sh.om[1][row][d2]
         + sh.om[2][row][d2]     + sh.om[3][row][d2])     * rls;
    v.y = (sh.om[0][row][d2 + 1] + sh.om[1][row][d2 + 1]
         + sh.om[2][row][d2 + 1] + sh.om[3][row][d2 + 1]) * rls;
    nts2(outO + ((size_t)bh * S_LEN + m0 + row) * D_HEAD + d2, v);
  }
}

// ---------------------------------------------------------------------------
extern "C" void kernel_launch(void* const* d_in, const int* in_sizes, int n_in,
                              void* d_out, int out_size, void* d_ws, size_t ws_size,
                              hipStream_t stream)
{
  const float* q     = (const float*)d_in[0];
  const float* kin   = (const float*)d_in[1];
  const float* vin   = (const float*)d_in[2];
  const float* prev  = (const float*)d_in[3];
  const float* scale = (const float*)d_in[4];

  float* O  = (float*)d_out;                                  // [32][2048][64]
  float* W  = O + (size_t)BH * S_LEN * D_HEAD;                // [32][2048][2048]
  float* Sc = W + (size_t)BH * S_LEN * S_LEN;                 // [32][2048][2048]

  unsigned short* kT = (unsigned short*)d_ws;                 // [32][2048][64] bf16
  unsigned short* vT = kT + (size_t)BH * S_LEN * D_HEAD;      // [32][64][2048] bf16

  dim3 tgrid(S_LEN / 64, BH, 2);
  hipLaunchKernelGGL(transpose_kernel, tgrid, dim3(256), 0, stream, kin, vin, kT, vT);

  dim3 grid(S_LEN / ROWS, BH);
  hipLaunchKernelGGL(fused_kernel, grid, dim3(256), 0, stream,
                     q, kT, prev, scale, vT, Sc, W, O);
}

// Round 10
// 480.430 us; speedup vs baseline: 1.4458x; 1.4458x over previous
//
#include <hip/hip_runtime.h>
#include <math.h>

// Problem dims
#define S_LEN 2048
#define D_HEAD 64
#define BH 32
#define ROWS 16     // strip rows per block; 66KB LDS -> 2 blocks/CU, 8 waves/block

typedef __attribute__((ext_vector_type(8))) short short8;    // 8 bf16 (4 VGPR)
typedef __attribute__((ext_vector_type(4))) short short4v;   // 8B LDS chunk
typedef __attribute__((ext_vector_type(4))) float f32x4;
typedef __attribute__((ext_vector_type(2))) float f32x2;

// LDS row stride in bf16 elems: 4104B rows -> 8B aligned, +2-bank row shift
#define SPAD 2052

__device__ __forceinline__ short f2bf(float f) {
  union { float f; unsigned u; } a; a.f = f;
  unsigned u = a.u;
  unsigned r = (u + 0x7fffu + ((u >> 16) & 1u)) >> 16;   // RNE, no NaNs here
  return (short)r;
}
__device__ __forceinline__ float bf2f(unsigned short h) {
  union { unsigned u; float f; } a; a.u = ((unsigned)h) << 16; return a.f;
}
__device__ __forceinline__ f32x4 ntl4(const float* p) { return __builtin_nontemporal_load((const f32x4*)p); }
__device__ __forceinline__ void  nts4(float* p, f32x4 v) { __builtin_nontemporal_store(v, (f32x4*)p); }
__device__ __forceinline__ void  nts2(float* p, f32x2 v) { __builtin_nontemporal_store(v, (f32x2*)p); }

// ---------------------------------------------------------------------------
// Kernel T: K [bh][64][2048] -> kT [bh][2048][64] bf16 ; V [bh][2048][64] ->
// vT [bh][64][2048] bf16. Fully coalesced both sides.
// ---------------------------------------------------------------------------
__global__ __launch_bounds__(256) void transpose_kernel(
    const float* __restrict__ kin, const float* __restrict__ vin,
    unsigned short* __restrict__ kT, unsigned short* __restrict__ vT)
{
  __shared__ float tile[64][65];
  const int bh = blockIdx.y;
  const int bx = blockIdx.x;
  const int t  = threadIdx.x;

  if (blockIdx.z == 0) {
    const float* in = kin + (size_t)bh * D_HEAD * S_LEN;
    #pragma unroll
    for (int p = 0; p < 4; ++p) {
      const int row = p * 16 + (t >> 4);
      f32x4 f = ntl4(in + (size_t)row * S_LEN + bx * 64 + (t & 15) * 4);
      tile[row][(t & 15) * 4 + 0] = f.x; tile[row][(t & 15) * 4 + 1] = f.y;
      tile[row][(t & 15) * 4 + 2] = f.z; tile[row][(t & 15) * 4 + 3] = f.w;
    }
    __syncthreads();
    union { unsigned short h[16]; uint4 q[2]; } u;
    #pragma unroll
    for (int i = 0; i < 16; ++i) u.h[i] = (unsigned short)f2bf(tile[(t & 3) * 16 + i][t >> 2]);
    uint4* dst = (uint4*)(kT + (size_t)bh * S_LEN * D_HEAD
                             + (size_t)(bx * 64 + (t >> 2)) * D_HEAD + (t & 3) * 16);
    dst[0] = u.q[0]; dst[1] = u.q[1];
  } else {
    const float* in = vin + (size_t)bh * S_LEN * D_HEAD;
    #pragma unroll
    for (int p = 0; p < 4; ++p) {
      const int row = p * 16 + (t >> 4);
      f32x4 f = ntl4(in + (size_t)(bx * 64 + row) * D_HEAD + (t & 15) * 4);
      tile[row][(t & 15) * 4 + 0] = f.x; tile[row][(t & 15) * 4 + 1] = f.y;
      tile[row][(t & 15) * 4 + 2] = f.z; tile[row][(t & 15) * 4 + 3] = f.w;
    }
    __syncthreads();
    union { unsigned short h[16]; uint4 q[2]; } u;
    #pragma unroll
    for (int i = 0; i < 16; ++i) u.h[i] = (unsigned short)f2bf(tile[(t & 3) * 16 + i][t >> 2]);
    uint4* dst = (uint4*)(vT + (size_t)bh * D_HEAD * S_LEN
                             + (size_t)(t >> 2) * S_LEN + bx * 64 + (t & 3) * 16);
    dst[0] = u.q[0]; dst[1] = u.q[1];
  }
}

// ---------------------------------------------------------------------------
// Fused kernel: 16-row strip / block, 512 threads = 8 waves col-split 256,
// 2 blocks/CU -> 16 waves/CU = 4/SIMD (latency hiding without dup work).
//  P1 : QK^T MFMA -> bf16(qk) into LDS (C-layout scatter)
//  P2 : coalesced (32 lanes per row, thread = 4 consecutive floats -> 512B
//       contiguous per instr): prev NT load, s = qk*scale+prev, scores NT
//       store, e = exp(s) -> LDS, row-sum via 5 shfl_xor (aligned 32-group).
//  P3+P4 fused: weights = e*rl NT store (HBM) interleaved with PV MFMA
//       (A = e from LDS, B = vT via L2).
//  Epilogue: merge 8 waves' partial O via LDS alias, scale by rl, NT store.
// ---------------------------------------------------------------------------
__global__ __launch_bounds__(512, 4) void fused_kernel(
    const float* __restrict__ q, const unsigned short* __restrict__ kT,
    const float* __restrict__ prev, const float* __restrict__ scale_p,
    const unsigned short* __restrict__ vT,
    float* __restrict__ scores, float* __restrict__ weights, float* __restrict__ outO)
{
  __shared__ union {
    unsigned short s[ROWS][SPAD];   // 65664 B
    float om[8][ROWS][68];          // 34816 B (aliased after P4 LDS reads)
  } sh;
  __shared__ float rlv[ROWS];

  const int bh   = blockIdx.y;
  const int m0   = blockIdx.x * ROWS;
  const int tid  = threadIdx.x;
  const int w    = tid >> 6;         // 0..7
  const int lane = tid & 63;
  const int lr   = lane & 15;
  const int lg   = lane >> 4;
  const float scale = scale_p[0];

  // Q A-frags: row = m0 + lr, d = kk*32 + lg*8 + j
  short8 aq[2];
  {
    const float* qrow = q + ((size_t)bh * S_LEN + m0 + lr) * D_HEAD;
    #pragma unroll
    for (int kk = 0; kk < 2; ++kk) {
      f32x4 f0 = *(const f32x4*)(qrow + kk * 32 + lg * 8);
      f32x4 f1 = *(const f32x4*)(qrow + kk * 32 + lg * 8 + 4);
      short8 a;
      a[0]=f2bf(f0.x); a[1]=f2bf(f0.y); a[2]=f2bf(f0.z); a[3]=f2bf(f0.w);
      a[4]=f2bf(f1.x); a[5]=f2bf(f1.y); a[6]=f2bf(f1.z); a[7]=f2bf(f1.w);
      aq[kk] = a;
    }
  }

  // P2 mapping: row owned by an aligned 32-lane group; thread = 4 consecutive
  // floats; one instruction = 32 lanes x 16B = 512B contiguous (full lines).
  const int row = tid >> 5;          // 0..15
  const int cq  = (tid & 31) * 4;    // 0..124
  const size_t rowoff = (size_t)bh * S_LEN * S_LEN + (size_t)(m0 + row) * S_LEN;
  const float* prevrow = prev + rowoff;
  // prefetch prev u=0..3 (in flight across all of P1)
  f32x4 pf0 = ntl4(prevrow + cq);
  f32x4 pf1 = ntl4(prevrow + cq + 128);
  f32x4 pf2 = ntl4(prevrow + cq + 256);
  f32x4 pf3 = ntl4(prevrow + cq + 384);

  const unsigned short* kbase = kT + (size_t)bh * S_LEN * D_HEAD;

  // ---------------- P1: QK^T -> LDS (bf16 raw products) ----------------
  // wave w owns cols [w*256, w*256+256): 4 t8-iters of 64 cols
  #pragma unroll 2
  for (int t8 = 0; t8 < 4; ++t8) {
    const int n0 = w * 256 + t8 * 64;
    f32x4 acc[4];
    #pragma unroll
    for (int nt = 0; nt < 4; ++nt) acc[nt] = (f32x4){0.f, 0.f, 0.f, 0.f};

    #pragma unroll
    for (int kk = 0; kk < 2; ++kk) {
      #pragma unroll
      for (int nt = 0; nt < 4; ++nt) {
        const short8 b = *(const short8*)(
            kbase + (size_t)(n0 + nt * 16 + lr) * D_HEAD + kk * 32 + lg * 8);
        acc[nt] = __builtin_amdgcn_mfma_f32_16x16x32_bf16(aq[kk], b, acc[nt], 0, 0, 0);
      }
    }
    #pragma unroll
    for (int nt = 0; nt < 4; ++nt)
      #pragma unroll
      for (int rg = 0; rg < 4; ++rg)
        sh.s[lg * 4 + rg][n0 + nt * 16 + lr] = (unsigned short)f2bf(acc[nt][rg]);
  }
  __syncthreads();

  // ---------------- P2: scores out + e=exp(s) into LDS + row-sum ----------
  float* srow = scores + rowoff;
  float sum = 0.f;
  #pragma unroll 4
  for (int u = 0; u < 16; ++u) {
    const int c = cq + u * 128;
    short4v h = *(const short4v*)&sh.s[row][c];
    f32x4 p = (u == 0) ? pf0 : (u == 1) ? pf1 : (u == 2) ? pf2 : (u == 3) ? pf3
                       : ntl4(prevrow + c);
    f32x4 s;
    s.x = bf2f((unsigned short)h[0]) * scale + p.x;
    s.y = bf2f((unsigned short)h[1]) * scale + p.y;
    s.z = bf2f((unsigned short)h[2]) * scale + p.z;
    s.w = bf2f((unsigned short)h[3]) * scale + p.w;
    nts4(srow + c, s);
    const float e0 = __expf(s.x), e1 = __expf(s.y), e2 = __expf(s.z), e3 = __expf(s.w);
    sum += (e0 + e1) + (e2 + e3);
    short4v g;
    g[0] = f2bf(e0); g[1] = f2bf(e1); g[2] = f2bf(e2); g[3] = f2bf(e3);
    *(short4v*)&sh.s[row][c] = g;
  }

  // row-sum across the 32-lane group (same wave, aligned)
  #pragma unroll
  for (int msk = 1; msk <= 16; msk <<= 1)
    sum += __shfl_xor(sum, msk, 64);
  const float rl = 1.0f / sum;
  if ((tid & 31) == 0) rlv[row] = rl;
  __syncthreads();

  // ---------------- P3+P4 fused: weights store ∥ PV MFMA ----------------
  const unsigned short* vbase = vT + (size_t)bh * D_HEAD * S_LEN;
  float* wrow = weights + rowoff;
  f32x4 accp[4];
  #pragma unroll
  for (int ct = 0; ct < 4; ++ct) accp[ct] = (f32x4){0.f, 0.f, 0.f, 0.f};

  #pragma unroll 2
  for (int i = 0; i < 8; ++i) {
    // P4 part: A = e fragment from LDS, B = vT (L2); wave w cols w*256..+256
    const int c4 = w * 256 + i * 32 + lg * 8;
    short4v h0 = *(const short4v*)&sh.s[lr][c4];
    short4v h1 = *(const short4v*)&sh.s[lr][c4 + 4];
    short8 a;
    a[0]=h0[0]; a[1]=h0[1]; a[2]=h0[2]; a[3]=h0[3];
    a[4]=h1[0]; a[5]=h1[1]; a[6]=h1[2]; a[7]=h1[3];
    #pragma unroll
    for (int ct = 0; ct < 4; ++ct) {
      const short8 b = *(const short8*)(vbase + (size_t)(ct * 16 + lr) * S_LEN + c4);
      accp[ct] = __builtin_amdgcn_mfma_f32_16x16x32_bf16(a, b, accp[ct], 0, 0, 0);
    }
    // P3 part: weights = e * rl (own row; 2 chunks per iter)
    #pragma unroll
    for (int v2 = 0; v2 < 2; ++v2) {
      const int c = cq + (i * 2 + v2) * 128;
      short4v hw = *(const short4v*)&sh.s[row][c];
      f32x4 e;
      e.x = bf2f((unsigned short)hw[0]) * rl;
      e.y = bf2f((unsigned short)hw[1]) * rl;
      e.z = bf2f((unsigned short)hw[2]) * rl;
      e.w = bf2f((unsigned short)hw[3]) * rl;
      nts4(wrow + c, e);
    }
  }
  __syncthreads();   // all sh.s reads done; safe to alias sh.om

  #pragma unroll
  for (int ct = 0; ct < 4; ++ct)
    #pragma unroll
    for (int rg = 0; rg < 4; ++rg)
      sh.om[w][lg * 4 + rg][ct * 16 + lr] = accp[ct][rg];
  __syncthreads();

  {
    const int d2  = (tid & 31) * 2;
    const float rls = rlv[row];
    f32x2 v;
    v.x = 0.f; v.y = 0.f;
    #pragma unroll
    for (int ww = 0; ww < 8; ++ww) {
      v.x += sh.om[ww][row][d2];
      v.y += sh.om[ww][row][d2 + 1];
    }
    v.x *= rls; v.y *= rls;
    nts2(outO + ((size_t)bh * S_LEN + m0 + row) * D_HEAD + d2, v);
  }
}

// ---------------------------------------------------------------------------
extern "C" void kernel_launch(void* const* d_in, const int* in_sizes, int n_in,
                              void* d_out, int out_size, void* d_ws, size_t ws_size,
                              hipStream_t stream)
{
  const float* q     = (const float*)d_in[0];
  const float* kin   = (const float*)d_in[1];
  const float* vin   = (const float*)d_in[2];
  const float* prev  = (const float*)d_in[3];
  const float* scale = (const float*)d_in[4];

  float* O  = (float*)d_out;                                  // [32][2048][64]
  float* W  = O + (size_t)BH * S_LEN * D_HEAD;                // [32][2048][2048]
  float* Sc = W + (size_t)BH * S_LEN * S_LEN;                 // [32][2048][2048]

  unsigned short* kT = (unsigned short*)d_ws;                 // [32][2048][64] bf16
  unsigned short* vT = kT + (size_t)BH * S_LEN * D_HEAD;      // [32][64][2048] bf16

  dim3 tgrid(S_LEN / 64, BH, 2);
  hipLaunchKernelGGL(transpose_kernel, tgrid, dim3(256), 0, stream, kin, vin, kT, vT);

  dim3 grid(S_LEN / ROWS, BH);
  hipLaunchKernelGGL(fused_kernel, grid, dim3(512), 0, stream,
                     q, kT, prev, scale, vT, Sc, W, O);
}

// Round 11
// 470.742 us; speedup vs baseline: 1.4756x; 1.0206x over previous
//
#include <hip/hip_runtime.h>
#include <math.h>

// Problem dims
#define S_LEN 2048
#define D_HEAD 64
#define BH 32
#define ROWS 16

typedef __attribute__((ext_vector_type(8))) short short8;    // 8 bf16 (4 VGPR)
typedef __attribute__((ext_vector_type(4))) short short4v;   // 8B LDS chunk
typedef __attribute__((ext_vector_type(4))) float f32x4;

// LDS row stride in bf16 elems: 4104B rows -> 8B aligned, +2-bank row shift
#define SPAD 2052

__device__ __forceinline__ short f2bf(float f) {
  union { float f; unsigned u; } a; a.f = f;
  unsigned u = a.u;
  unsigned r = (u + 0x7fffu + ((u >> 16) & 1u)) >> 16;   // RNE, no NaNs here
  return (short)r;
}
__device__ __forceinline__ float bf2f(unsigned short h) {
  union { unsigned u; float f; } a; a.u = ((unsigned)h) << 16; return a.f;
}
// R10: plain cached loads/stores (A/B test vs R7's non-temporal flags)
__device__ __forceinline__ f32x4 ld4(const float* p) { return *(const f32x4*)p; }
__device__ __forceinline__ void  st4(float* p, f32x4 v) { *(f32x4*)p = v; }

// ---------------------------------------------------------------------------
// Kernel T: K [bh][64][2048] -> kT [bh][2048][64] bf16 ; V [bh][2048][64] ->
// vT [bh][64][2048] bf16. Fully coalesced both sides.
// ---------------------------------------------------------------------------
__global__ __launch_bounds__(256) void transpose_kernel(
    const float* __restrict__ kin, const float* __restrict__ vin,
    unsigned short* __restrict__ kT, unsigned short* __restrict__ vT)
{
  __shared__ float tile[64][65];
  const int bh = blockIdx.y;
  const int bx = blockIdx.x;
  const int t  = threadIdx.x;

  if (blockIdx.z == 0) {
    const float* in = kin + (size_t)bh * D_HEAD * S_LEN;
    #pragma unroll
    for (int p = 0; p < 4; ++p) {
      const int row = p * 16 + (t >> 4);
      f32x4 f = ld4(in + (size_t)row * S_LEN + bx * 64 + (t & 15) * 4);
      tile[row][(t & 15) * 4 + 0] = f.x; tile[row][(t & 15) * 4 + 1] = f.y;
      tile[row][(t & 15) * 4 + 2] = f.z; tile[row][(t & 15) * 4 + 3] = f.w;
    }
    __syncthreads();
    union { unsigned short h[16]; uint4 q[2]; } u;
    #pragma unroll
    for (int i = 0; i < 16; ++i) u.h[i] = (unsigned short)f2bf(tile[(t & 3) * 16 + i][t >> 2]);
    uint4* dst = (uint4*)(kT + (size_t)bh * S_LEN * D_HEAD
                             + (size_t)(bx * 64 + (t >> 2)) * D_HEAD + (t & 3) * 16);
    dst[0] = u.q[0]; dst[1] = u.q[1];
  } else {
    const float* in = vin + (size_t)bh * S_LEN * D_HEAD;
    #pragma unroll
    for (int p = 0; p < 4; ++p) {
      const int row = p * 16 + (t >> 4);
      f32x4 f = ld4(in + (size_t)(bx * 64 + row) * D_HEAD + (t & 15) * 4);
      tile[row][(t & 15) * 4 + 0] = f.x; tile[row][(t & 15) * 4 + 1] = f.y;
      tile[row][(t & 15) * 4 + 2] = f.z; tile[row][(t & 15) * 4 + 3] = f.w;
    }
    __syncthreads();
    union { unsigned short h[16]; uint4 q[2]; } u;
    #pragma unroll
    for (int i = 0; i < 16; ++i) u.h[i] = (unsigned short)f2bf(tile[(t & 3) * 16 + i][t >> 2]);
    uint4* dst = (uint4*)(vT + (size_t)bh * D_HEAD * S_LEN
                             + (size_t)(t >> 2) * S_LEN + bx * 64 + (t & 3) * 16);
    dst[0] = u.q[0]; dst[1] = u.q[1];
  }
}

// ---------------------------------------------------------------------------
// Fused kernel, identical to R7 (461us best) EXCEPT all global accesses are
// plain cached loads/stores (NT flags removed) — isolates the NT-flag effect.
// 16-row strip / block, 4 waves col-split 512, 2 blocks/CU.
// ---------------------------------------------------------------------------
__global__ __launch_bounds__(256, 2) void fused_kernel(
    const float* __restrict__ q, const unsigned short* __restrict__ kT,
    const float* __restrict__ prev, const float* __restrict__ scale_p,
    const unsigned short* __restrict__ vT,
    float* __restrict__ scores, float* __restrict__ weights, float* __restrict__ outO)
{
  __shared__ union {
    unsigned short s[ROWS][SPAD];   // 65664 B
    float om[4][ROWS][68];          // aliased after P4's LDS reads
  } sh;
  __shared__ float rlv[ROWS];

  const int bh   = blockIdx.y;
  const int m0   = blockIdx.x * ROWS;
  const int tid  = threadIdx.x;
  const int w    = tid >> 6;
  const int lane = tid & 63;
  const int lr   = lane & 15;
  const int lg   = lane >> 4;
  const float scale = scale_p[0];

  // Q A-frags: row = m0+lr, d = kk*32 + lg*8 + j
  short8 aq[2];
  {
    const float* qrow = q + ((size_t)bh * S_LEN + m0 + lr) * D_HEAD;
    #pragma unroll
    for (int kk = 0; kk < 2; ++kk) {
      f32x4 f0 = *(const f32x4*)(qrow + kk * 32 + lg * 8);
      f32x4 f1 = *(const f32x4*)(qrow + kk * 32 + lg * 8 + 4);
      short8 a;
      a[0]=f2bf(f0.x); a[1]=f2bf(f0.y); a[2]=f2bf(f0.z); a[3]=f2bf(f0.w);
      a[4]=f2bf(f1.x); a[5]=f2bf(f1.y); a[6]=f2bf(f1.z); a[7]=f2bf(f1.w);
      aq[kk] = a;
    }
  }

  // P2 mapping: row owned by an aligned 16-lane group of one wave
  const int row = tid >> 4;          // 0..15
  const int cq  = (tid & 15) * 4;    // 0..60
  const size_t rowoff = (size_t)bh * S_LEN * S_LEN + (size_t)(m0 + row) * S_LEN;
  const float* prevrow = prev + rowoff;
  // prefetch prev for u=0,1 (in flight across all of P1)
  f32x4 pf0 = ld4(prevrow + cq);
  f32x4 pf1 = ld4(prevrow + cq + 1024);
  f32x4 pf2 = ld4(prevrow + cq + 64);
  f32x4 pf3 = ld4(prevrow + cq + 64 + 1024);

  const unsigned short* kbase = kT + (size_t)bh * S_LEN * D_HEAD;

  // ---------------- P1: QK^T -> LDS (bf16 raw products) ----------------
  #pragma unroll 2
  for (int t8 = 0; t8 < 8; ++t8) {
    const int n0 = w * 512 + t8 * 64;
    f32x4 acc[4];
    #pragma unroll
    for (int nt = 0; nt < 4; ++nt) acc[nt] = (f32x4){0.f, 0.f, 0.f, 0.f};

    #pragma unroll
    for (int kk = 0; kk < 2; ++kk) {
      #pragma unroll
      for (int nt = 0; nt < 4; ++nt) {
        const short8 b = *(const short8*)(
            kbase + (size_t)(n0 + nt * 16 + lr) * D_HEAD + kk * 32 + lg * 8);
        acc[nt] = __builtin_amdgcn_mfma_f32_16x16x32_bf16(aq[kk], b, acc[nt], 0, 0, 0);
      }
    }
    #pragma unroll
    for (int nt = 0; nt < 4; ++nt)
      #pragma unroll
      for (int rg = 0; rg < 4; ++rg)
        sh.s[lg * 4 + rg][n0 + nt * 16 + lr] = (unsigned short)f2bf(acc[nt][rg]);
  }
  __syncthreads();

  // ---------------- P2: scores out + e=exp(s) into LDS + row-sum ----------
  float* srow = scores + rowoff;
  float sum = 0.f;
  #pragma unroll 4
  for (int u = 0; u < 16; ++u) {
    const int cA = cq + u * 64;
    const int cB = cA + 1024;
    short4v hA = *(const short4v*)&sh.s[row][cA];
    short4v hB = *(const short4v*)&sh.s[row][cB];
    f32x4 pA = (u == 0) ? pf0 : (u == 1) ? pf2 : ld4(prevrow + cA);
    f32x4 pB = (u == 0) ? pf1 : (u == 1) ? pf3 : ld4(prevrow + cB);
    f32x4 sA, sB;
    sA.x = bf2f((unsigned short)hA[0]) * scale + pA.x;
    sA.y = bf2f((unsigned short)hA[1]) * scale + pA.y;
    sA.z = bf2f((unsigned short)hA[2]) * scale + pA.z;
    sA.w = bf2f((unsigned short)hA[3]) * scale + pA.w;
    sB.x = bf2f((unsigned short)hB[0]) * scale + pB.x;
    sB.y = bf2f((unsigned short)hB[1]) * scale + pB.y;
    sB.z = bf2f((unsigned short)hB[2]) * scale + pB.z;
    sB.w = bf2f((unsigned short)hB[3]) * scale + pB.w;
    st4(srow + cA, sA);
    st4(srow + cB, sB);
    const float e0 = __expf(sA.x), e1 = __expf(sA.y), e2 = __expf(sA.z), e3 = __expf(sA.w);
    const float e4 = __expf(sB.x), e5 = __expf(sB.y), e6 = __expf(sB.z), e7 = __expf(sB.w);
    sum += ((e0 + e1) + (e2 + e3)) + ((e4 + e5) + (e6 + e7));
    short4v gA, gB;
    gA[0]=f2bf(e0); gA[1]=f2bf(e1); gA[2]=f2bf(e2); gA[3]=f2bf(e3);
    gB[0]=f2bf(e4); gB[1]=f2bf(e5); gB[2]=f2bf(e6); gB[3]=f2bf(e7);
    *(short4v*)&sh.s[row][cA] = gA;
    *(short4v*)&sh.s[row][cB] = gB;
  }

  // row-sum across the 16-lane group (same wave, aligned)
  #pragma unroll
  for (int msk = 1; msk <= 8; msk <<= 1)
    sum += __shfl_xor(sum, msk, 64);
  const float rl = 1.0f / sum;
  if ((tid & 15) == 0) rlv[row] = rl;
  __syncthreads();

  // ---------------- P3+P4 fused: weights store ∥ PV MFMA ----------------
  const unsigned short* vbase = vT + (size_t)bh * D_HEAD * S_LEN;
  float* wrow = weights + rowoff;
  f32x4 accp[4];
  #pragma unroll
  for (int ct = 0; ct < 4; ++ct) accp[ct] = (f32x4){0.f, 0.f, 0.f, 0.f};

  #pragma unroll 2
  for (int i = 0; i < 16; ++i) {
    // P4 part: A = e fragment from LDS, B = vT (L2)
    const int c4 = w * 512 + i * 32 + lg * 8;
    short4v h0 = *(const short4v*)&sh.s[lr][c4];
    short4v h1 = *(const short4v*)&sh.s[lr][c4 + 4];
    short8 a;
    a[0]=h0[0]; a[1]=h0[1]; a[2]=h0[2]; a[3]=h0[3];
    a[4]=h1[0]; a[5]=h1[1]; a[6]=h1[2]; a[7]=h1[3];
    #pragma unroll
    for (int ct = 0; ct < 4; ++ct) {
      const short8 b = *(const short8*)(vbase + (size_t)(ct * 16 + lr) * S_LEN + c4);
      accp[ct] = __builtin_amdgcn_mfma_f32_16x16x32_bf16(a, b, accp[ct], 0, 0, 0);
    }
    // P3 part: weights = e * rl (own row, independent of P4)
    const int cA = cq + i * 64;
    const int cB = cA + 1024;
    short4v wA = *(const short4v*)&sh.s[row][cA];
    short4v wB = *(const short4v*)&sh.s[row][cB];
    f32x4 eA, eB;
    eA.x = bf2f((unsigned short)wA[0]) * rl;
    eA.y = bf2f((unsigned short)wA[1]) * rl;
    eA.z = bf2f((unsigned short)wA[2]) * rl;
    eA.w = bf2f((unsigned short)wA[3]) * rl;
    eB.x = bf2f((unsigned short)wB[0]) * rl;
    eB.y = bf2f((unsigned short)wB[1]) * rl;
    eB.z = bf2f((unsigned short)wB[2]) * rl;
    eB.w = bf2f((unsigned short)wB[3]) * rl;
    st4(wrow + cA, eA);
    st4(wrow + cB, eB);
  }
  __syncthreads();   // all sh.s reads done; safe to alias sh.om

  #pragma unroll
  for (int ct = 0; ct < 4; ++ct)
    #pragma unroll
    for (int rg = 0; rg < 4; ++rg)
      sh.om[w][lg * 4 + rg][ct * 16 + lr] = accp[ct][rg];
  __syncthreads();

  {
    const int d4 = (tid & 15) * 4;
    const float rls = rlv[row];
    f32x4 v;
    #pragma unroll
    for (int i = 0; i < 4; ++i)
      v[i] = (sh.om[0][row][d4 + i] + sh.om[1][row][d4 + i]
            + sh.om[2][row][d4 + i] + sh.om[3][row][d4 + i]) * rls;
    st4(outO + ((size_t)bh * S_LEN + m0 + row) * D_HEAD + d4, v);
  }
}

// ---------------------------------------------------------------------------
extern "C" void kernel_launch(void* const* d_in, const int* in_sizes, int n_in,
                              void* d_out, int out_size, void* d_ws, size_t ws_size,
                              hipStream_t stream)
{
  const float* q     = (const float*)d_in[0];
  const float* kin   = (const float*)d_in[1];
  const float* vin   = (const float*)d_in[2];
  const float* prev  = (const float*)d_in[3];
  const float* scale = (const float*)d_in[4];

  float* O  = (float*)d_out;                                  // [32][2048][64]
  float* W  = O + (size_t)BH * S_LEN * D_HEAD;                // [32][2048][2048]
  float* Sc = W + (size_t)BH * S_LEN * S_LEN;                 // [32][2048][2048]

  unsigned short* kT = (unsigned short*)d_ws;                 // [32][2048][64] bf16
  unsigned short* vT = kT + (size_t)BH * S_LEN * D_HEAD;      // [32][64][2048] bf16

  dim3 tgrid(S_LEN / 64, BH, 2);
  hipLaunchKernelGGL(transpose_kernel, tgrid, dim3(256), 0, stream, kin, vin, kT, vT);

  dim3 grid(S_LEN / ROWS, BH);
  hipLaunchKernelGGL(fused_kernel, grid, dim3(256), 0, stream,
                     q, kT, prev, scale, vT, Sc, W, O);
}

// Round 12
// 418.778 us; speedup vs baseline: 1.6587x; 1.1241x over previous
//
#include <hip/hip_runtime.h>
#include <math.h>

// Problem dims
#define S_LEN 2048
#define D_HEAD 64
#define BH 32
#define ROWS 16

typedef __attribute__((ext_vector_type(8))) short short8;    // 8 bf16 (4 VGPR)
typedef __attribute__((ext_vector_type(4))) short short4v;   // 8B LDS chunk
typedef __attribute__((ext_vector_type(4))) float f32x4;

// LDS row stride in bf16 elems: 4104B rows -> 8B aligned, +2-bank row shift
#define SPAD 2052

__device__ __forceinline__ short f2bf(float f) {
  union { float f; unsigned u; } a; a.f = f;
  unsigned u = a.u;
  unsigned r = (u + 0x7fffu + ((u >> 16) & 1u)) >> 16;   // RNE, no NaNs here
  return (short)r;
}
__device__ __forceinline__ float bf2f(unsigned short h) {
  union { unsigned u; float f; } a; a.u = ((unsigned)h) << 16; return a.f;
}
__device__ __forceinline__ f32x4 ntl4(const float* p) { return __builtin_nontemporal_load((const f32x4*)p); }
__device__ __forceinline__ void  nts4(float* p, f32x4 v) { __builtin_nontemporal_store(v, (f32x4*)p); }

// ---------------------------------------------------------------------------
// Kernel T: K [bh][64][2048] -> kT [bh][2048][64] bf16 ; V [bh][2048][64] ->
// vT [bh][64][2048] bf16. Fully coalesced both sides.
// ---------------------------------------------------------------------------
__global__ __launch_bounds__(256) void transpose_kernel(
    const float* __restrict__ kin, const float* __restrict__ vin,
    unsigned short* __restrict__ kT, unsigned short* __restrict__ vT)
{
  __shared__ float tile[64][65];
  const int bh = blockIdx.y;
  const int bx = blockIdx.x;
  const int t  = threadIdx.x;

  if (blockIdx.z == 0) {
    const float* in = kin + (size_t)bh * D_HEAD * S_LEN;
    #pragma unroll
    for (int p = 0; p < 4; ++p) {
      const int row = p * 16 + (t >> 4);
      f32x4 f = ntl4(in + (size_t)row * S_LEN + bx * 64 + (t & 15) * 4);
      tile[row][(t & 15) * 4 + 0] = f.x; tile[row][(t & 15) * 4 + 1] = f.y;
      tile[row][(t & 15) * 4 + 2] = f.z; tile[row][(t & 15) * 4 + 3] = f.w;
    }
    __syncthreads();
    union { unsigned short h[16]; uint4 q[2]; } u;
    #pragma unroll
    for (int i = 0; i < 16; ++i) u.h[i] = (unsigned short)f2bf(tile[(t & 3) * 16 + i][t >> 2]);
    uint4* dst = (uint4*)(kT + (size_t)bh * S_LEN * D_HEAD
                             + (size_t)(bx * 64 + (t >> 2)) * D_HEAD + (t & 3) * 16);
    dst[0] = u.q[0]; dst[1] = u.q[1];
  } else {
    const float* in = vin + (size_t)bh * S_LEN * D_HEAD;
    #pragma unroll
    for (int p = 0; p < 4; ++p) {
      const int row = p * 16 + (t >> 4);
      f32x4 f = ntl4(in + (size_t)(bx * 64 + row) * D_HEAD + (t & 15) * 4);
      tile[row][(t & 15) * 4 + 0] = f.x; tile[row][(t & 15) * 4 + 1] = f.y;
      tile[row][(t & 15) * 4 + 2] = f.z; tile[row][(t & 15) * 4 + 3] = f.w;
    }
    __syncthreads();
    union { unsigned short h[16]; uint4 q[2]; } u;
    #pragma unroll
    for (int i = 0; i < 16; ++i) u.h[i] = (unsigned short)f2bf(tile[(t & 3) * 16 + i][t >> 2]);
    uint4* dst = (uint4*)(vT + (size_t)bh * D_HEAD * S_LEN
                             + (size_t)(t >> 2) * S_LEN + bx * 64 + (t & 3) * 16);
    dst[0] = u.q[0]; dst[1] = u.q[1];
  }
}

// ---------------------------------------------------------------------------
// Fused kernel = R7 structure + 16-deep prev prefetch issued BEFORE P1.
// 16-row strip / block, 4 waves col-split 512, 2 blocks/CU.
//  pre : issue 16 prev f32x4 loads (64 VGPRs) -> HBM active during P1
//  P1  : QK^T MFMA -> bf16(qk) into LDS (C-layout scatter)
//  P2  : 32 sequential chunks; consume pf[u&15], issue load u+16 ->
//        always ~16 loads in flight; scores NT store; e=exp -> LDS; row-sum.
//  P3+P4 fused: weights = e*rl NT store ∥ PV MFMA (A from LDS, B = vT L2).
//  Epilogue: merge 4 waves' partial O via LDS alias, scale by rl, NT store.
// ---------------------------------------------------------------------------
__global__ __launch_bounds__(256, 2) void fused_kernel(
    const float* __restrict__ q, const unsigned short* __restrict__ kT,
    const float* __restrict__ prev, const float* __restrict__ scale_p,
    const unsigned short* __restrict__ vT,
    float* __restrict__ scores, float* __restrict__ weights, float* __restrict__ outO)
{
  __shared__ union {
    unsigned short s[ROWS][SPAD];   // 65664 B
    float om[4][ROWS][68];          // aliased after P4's LDS reads
  } sh;
  __shared__ float rlv[ROWS];

  const int bh   = blockIdx.y;
  const int m0   = blockIdx.x * ROWS;
  const int tid  = threadIdx.x;
  const int w    = tid >> 6;
  const int lane = tid & 63;
  const int lr   = lane & 15;
  const int lg   = lane >> 4;
  const float scale = scale_p[0];

  // P2 mapping: row owned by an aligned 16-lane group of one wave
  const int row = tid >> 4;          // 0..15
  const int cq  = (tid & 15) * 4;    // 0..60
  const size_t rowoff = (size_t)bh * S_LEN * S_LEN + (size_t)(m0 + row) * S_LEN;
  const float* prevrow = prev + rowoff;

  // ---- deep prefetch: 16 chunks (cols 0..1023 of this thread's row) ----
  f32x4 pf[16];
  #pragma unroll
  for (int u = 0; u < 16; ++u) pf[u] = ntl4(prevrow + cq + u * 64);

  // Q A-frags: row = m0+lr, d = kk*32 + lg*8 + j
  short8 aq[2];
  {
    const float* qrow = q + ((size_t)bh * S_LEN + m0 + lr) * D_HEAD;
    #pragma unroll
    for (int kk = 0; kk < 2; ++kk) {
      f32x4 f0 = *(const f32x4*)(qrow + kk * 32 + lg * 8);
      f32x4 f1 = *(const f32x4*)(qrow + kk * 32 + lg * 8 + 4);
      short8 a;
      a[0]=f2bf(f0.x); a[1]=f2bf(f0.y); a[2]=f2bf(f0.z); a[3]=f2bf(f0.w);
      a[4]=f2bf(f1.x); a[5]=f2bf(f1.y); a[6]=f2bf(f1.z); a[7]=f2bf(f1.w);
      aq[kk] = a;
    }
  }

  const unsigned short* kbase = kT + (size_t)bh * S_LEN * D_HEAD;

  // ---------------- P1: QK^T -> LDS (bf16 raw products) ----------------
  #pragma unroll 2
  for (int t8 = 0; t8 < 8; ++t8) {
    const int n0 = w * 512 + t8 * 64;
    f32x4 acc[4];
    #pragma unroll
    for (int nt = 0; nt < 4; ++nt) acc[nt] = (f32x4){0.f, 0.f, 0.f, 0.f};

    #pragma unroll
    for (int kk = 0; kk < 2; ++kk) {
      #pragma unroll
      for (int nt = 0; nt < 4; ++nt) {
        const short8 b = *(const short8*)(
            kbase + (size_t)(n0 + nt * 16 + lr) * D_HEAD + kk * 32 + lg * 8);
        acc[nt] = __builtin_amdgcn_mfma_f32_16x16x32_bf16(aq[kk], b, acc[nt], 0, 0, 0);
      }
    }
    #pragma unroll
    for (int nt = 0; nt < 4; ++nt)
      #pragma unroll
      for (int rg = 0; rg < 4; ++rg)
        sh.s[lg * 4 + rg][n0 + nt * 16 + lr] = (unsigned short)f2bf(acc[nt][rg]);
  }
  __syncthreads();

  // ---------------- P2: 32-chunk pipelined scores + e=exp(s) + row-sum ----
  float* srow = scores + rowoff;
  float sum = 0.f;
  #pragma unroll
  for (int u = 0; u < 32; ++u) {
    const int c = cq + u * 64;
    const f32x4 p = pf[u & 15];
    if (u < 16) pf[u & 15] = ntl4(prevrow + cq + (u + 16) * 64);  // keep 16 in flight
    short4v h = *(const short4v*)&sh.s[row][c];
    f32x4 s;
    s.x = bf2f((unsigned short)h[0]) * scale + p.x;
    s.y = bf2f((unsigned short)h[1]) * scale + p.y;
    s.z = bf2f((unsigned short)h[2]) * scale + p.z;
    s.w = bf2f((unsigned short)h[3]) * scale + p.w;
    nts4(srow + c, s);
    const float e0 = __expf(s.x), e1 = __expf(s.y), e2 = __expf(s.z), e3 = __expf(s.w);
    sum += (e0 + e1) + (e2 + e3);
    short4v g;
    g[0] = f2bf(e0); g[1] = f2bf(e1); g[2] = f2bf(e2); g[3] = f2bf(e3);
    *(short4v*)&sh.s[row][c] = g;
  }

  // row-sum across the 16-lane group (same wave, aligned)
  #pragma unroll
  for (int msk = 1; msk <= 8; msk <<= 1)
    sum += __shfl_xor(sum, msk, 64);
  const float rl = 1.0f / sum;
  if ((tid & 15) == 0) rlv[row] = rl;
  __syncthreads();

  // ---------------- P3+P4 fused: weights store ∥ PV MFMA ----------------
  const unsigned short* vbase = vT + (size_t)bh * D_HEAD * S_LEN;
  float* wrow = weights + rowoff;
  f32x4 accp[4];
  #pragma unroll
  for (int ct = 0; ct < 4; ++ct) accp[ct] = (f32x4){0.f, 0.f, 0.f, 0.f};

  #pragma unroll 2
  for (int i = 0; i < 16; ++i) {
    // P4 part: A = e fragment from LDS, B = vT (L2)
    const int c4 = w * 512 + i * 32 + lg * 8;
    short4v h0 = *(const short4v*)&sh.s[lr][c4];
    short4v h1 = *(const short4v*)&sh.s[lr][c4 + 4];
    short8 a;
    a[0]=h0[0]; a[1]=h0[1]; a[2]=h0[2]; a[3]=h0[3];
    a[4]=h1[0]; a[5]=h1[1]; a[6]=h1[2]; a[7]=h1[3];
    #pragma unroll
    for (int ct = 0; ct < 4; ++ct) {
      const short8 b = *(const short8*)(vbase + (size_t)(ct * 16 + lr) * S_LEN + c4);
      accp[ct] = __builtin_amdgcn_mfma_f32_16x16x32_bf16(a, b, accp[ct], 0, 0, 0);
    }
    // P3 part: weights = e * rl (own row, independent of P4)
    const int cA = cq + i * 64;
    const int cB = cA + 1024;
    short4v wA = *(const short4v*)&sh.s[row][cA];
    short4v wB = *(const short4v*)&sh.s[row][cB];
    f32x4 eA, eB;
    eA.x = bf2f((unsigned short)wA[0]) * rl;
    eA.y = bf2f((unsigned short)wA[1]) * rl;
    eA.z = bf2f((unsigned short)wA[2]) * rl;
    eA.w = bf2f((unsigned short)wA[3]) * rl;
    eB.x = bf2f((unsigned short)wB[0]) * rl;
    eB.y = bf2f((unsigned short)wB[1]) * rl;
    eB.z = bf2f((unsigned short)wB[2]) * rl;
    eB.w = bf2f((unsigned short)wB[3]) * rl;
    nts4(wrow + cA, eA);
    nts4(wrow + cB, eB);
  }
  __syncthreads();   // all sh.s reads done; safe to alias sh.om

  #pragma unroll
  for (int ct = 0; ct < 4; ++ct)
    #pragma unroll
    for (int rg = 0; rg < 4; ++rg)
      sh.om[w][lg * 4 + rg][ct * 16 + lr] = accp[ct][rg];
  __syncthreads();

  {
    const int d4 = (tid & 15) * 4;
    const float rls = rlv[row];
    f32x4 v;
    #pragma unroll
    for (int i = 0; i < 4; ++i)
      v[i] = (sh.om[0][row][d4 + i] + sh.om[1][row][d4 + i]
            + sh.om[2][row][d4 + i] + sh.om[3][row][d4 + i]) * rls;
    nts4(outO + ((size_t)bh * S_LEN + m0 + row) * D_HEAD + d4, v);
  }
}

// ---------------------------------------------------------------------------
extern "C" void kernel_launch(void* const* d_in, const int* in_sizes, int n_in,
                              void* d_out, int out_size, void* d_ws, size_t ws_size,
                              hipStream_t stream)
{
  const float* q     = (const float*)d_in[0];
  const float* kin   = (const float*)d_in[1];
  const float* vin   = (const float*)d_in[2];
  const float* prev  = (const float*)d_in[3];
  const float* scale = (const float*)d_in[4];

  float* O  = (float*)d_out;                                  // [32][2048][64]
  float* W  = O + (size_t)BH * S_LEN * D_HEAD;                // [32][2048][2048]
  float* Sc = W + (size_t)BH * S_LEN * S_LEN;                 // [32][2048][2048]

  unsigned short* kT = (unsigned short*)d_ws;                 // [32][2048][64] bf16
  unsigned short* vT = kT + (size_t)BH * S_LEN * D_HEAD;      // [32][64][2048] bf16

  dim3 tgrid(S_LEN / 64, BH, 2);
  hipLaunchKernelGGL(transpose_kernel, tgrid, dim3(256), 0, stream, kin, vin, kT, vT);

  dim3 grid(S_LEN / ROWS, BH);
  hipLaunchKernelGGL(fused_kernel, grid, dim3(256), 0, stream,
                     q, kT, prev, scale, vT, Sc, W, O);
}